// Round 4
// baseline (532.421 us; speedup 1.0000x reference)
//
#include <hip/hip_runtime.h>
#include <hip/hip_bf16.h>

typedef __attribute__((ext_vector_type(4))) float f32x4;
typedef __attribute__((ext_vector_type(8))) short short8;
typedef __attribute__((ext_vector_type(4))) unsigned short us4;

#define BH_ 128
#define N_ 4096
#define LOG2E 1.4426950408889634f
#define NORML (0.35355339059327373f * LOG2E)  // d^-0.25 * log2(e) folded into P
#define DIAGL (0.0625f * LOG2E)               // 0.5*d^-0.5 * log2(e)
#define EPSF 1e-4f

#if __has_builtin(__builtin_amdgcn_exp2f)
#define EXP2F(x) __builtin_amdgcn_exp2f(x)
#else
#define EXP2F(x) exp2f(x)
#endif

// LDS-only barrier: orders ds_write/ds_read across waves WITHOUT draining
// vmcnt — in-flight global prefetch loads survive the barrier (T4). Each
// wave drains its own lgkm (staging writes complete) before s_barrier, so
// post-barrier readers see the data; pre-barrier readers completed their
// ds_reads (same lgkmcnt(0)) so post-barrier writers can't clobber them.
#define BARRIER_LGKM() asm volatile("s_waitcnt lgkmcnt(0)\ns_barrier" ::: "memory")

static __device__ __forceinline__ unsigned short f2bf(float f) {
  return __bfloat16_as_ushort(__float2bfloat16(f));  // RNE, HW cvt
}
static __device__ __forceinline__ float bf2f(unsigned short s) {
  return __uint_as_float(((unsigned int)s) << 16);
}
static __device__ __forceinline__ us4 cvt4(f32x4 x) {
  us4 r;
  r[0] = f2bf(x[0]); r[1] = f2bf(x[1]); r[2] = f2bf(x[2]); r[3] = f2bf(x[3]);
  return r;
}
static __device__ __forceinline__ unsigned int pk2bf(float lo, float hi) {
  unsigned int r;
  asm("v_cvt_pk_bf16_f32 %0, %1, %2" : "=v"(r) : "v"(lo), "v"(hi));
  return r;
}

// ---------------------------------------------------------------------------
// prep: projection -> bf16 with NORML folded (consumed by qpass GEMM1).
// ---------------------------------------------------------------------------
__global__ void perf_prep(const float* __restrict__ proj,
                          unsigned short* __restrict__ projb) {
  int i = blockIdx.x * 256 + threadIdx.x;  // 16384 total
  projb[i] = f2bf(proj[i] * NORML);
}

// ---------------------------------------------------------------------------
// K pass (log2 domain) — structure as round 3, barriers now lgkm-only so the
// K/V register prefetch stays in flight across the whole tile compute.
// ---------------------------------------------------------------------------
__global__ __launch_bounds__(256, 2)
void perf_kpass(const float* __restrict__ kp, const float* __restrict__ vp,
                const float* __restrict__ proj, float* __restrict__ ctxp,
                float* __restrict__ kexpp, float* __restrict__ vsump,
                unsigned int* __restrict__ gmaxb, int nchunk) {
  const int bh = blockIdx.x & (BH_ - 1);
  const int chunk = blockIdx.x >> 7;
  const int chunkrows = N_ / nchunk;
  const int tiles = chunkrows >> 5;
  const int t = threadIdx.x;
  const int wid = t >> 6;
  const int lane = t & 63;
  const int g = lane >> 4;
  const int c = lane & 15;

  __shared__ __align__(16) unsigned short sX[32][72];
  __shared__ __align__(16) unsigned short sVt[64][40];
  __shared__ __align__(16) unsigned short sW[256][40];
  __shared__ float sDiag[32];
  __shared__ float sVsum[64];
  __shared__ float sGm[4];

  short8 pfrag[4][2];
#pragma unroll
  for (int mt = 0; mt < 4; ++mt)
#pragma unroll
    for (int kk = 0; kk < 2; ++kk) {
      const float* src = proj + (wid * 64 + mt * 16 + c) * 64 + kk * 32 + g * 8;
      short8 v;
#pragma unroll
      for (int j = 0; j < 8; ++j) v[j] = (short)f2bf(src[j] * NORML);
      pfrag[mt][kk] = v;
    }

  f32x4 ctx[4][4];
#pragma unroll
  for (int i = 0; i < 4; ++i)
#pragma unroll
    for (int j = 0; j < 4; ++j) ctx[i][j] = (f32x4){0.f, 0.f, 0.f, 0.f};

  float kexpreg[4] = {0.f, 0.f, 0.f, 0.f};
  float vsum0 = 0.f, vsum1 = 0.f, vsum2 = 0.f, vsum3 = 0.f;
  float gm = -1e30f;

  const float* kb0 = kp + ((size_t)bh * N_ + (size_t)chunk * chunkrows) * 64;
  const float* vb0 = vp + ((size_t)bh * N_ + (size_t)chunk * chunkrows) * 64;

  f32x4 kx[2], vx[2];
#pragma unroll
  for (int hh = 0; hh < 2; ++hh) {
    int f = t + hh * 256;
    kx[hh] = *(const f32x4*)(kb0 + (f >> 4) * 64 + (f & 15) * 4);
    vx[hh] = *(const f32x4*)(vb0 + (f >> 4) * 64 + (f & 15) * 4);
  }

  for (int nt = 0; nt < tiles; ++nt) {
    BARRIER_LGKM();  // S: prev tile's ds_reads done before overwrite
#pragma unroll
    for (int hh = 0; hh < 2; ++hh) {
      int f = t + hh * 256;
      int row = f >> 4;
      int c4 = f & 15;
      f32x4 x = kx[hh];
      float ss = x[0] * x[0] + x[1] * x[1] + x[2] * x[2] + x[3] * x[3];
      ss += __shfl_xor(ss, 1);
      ss += __shfl_xor(ss, 2);
      ss += __shfl_xor(ss, 4);
      ss += __shfl_xor(ss, 8);
      if (c4 == 0) sDiag[row] = DIAGL * ss;
      *(us4*)&sX[row][c4 * 4] = cvt4(x);
      f32x4 vv = vx[hh];
      vsum0 += vv[0]; vsum1 += vv[1]; vsum2 += vv[2]; vsum3 += vv[3];
#pragma unroll
      for (int jj = 0; jj < 4; ++jj) {
        int j = (jj + t) & 3;  // rotate to spread banks
        float val = (j == 0) ? vv[0] : (j == 1) ? vv[1] : (j == 2) ? vv[2] : vv[3];
        sVt[c4 * 4 + j][row] = f2bf(val);
      }
    }
    if (nt + 1 < tiles) {  // prefetch survives the lgkm-only barrier below
      const float* kb = kb0 + (nt + 1) * 2048;
      const float* vb = vb0 + (nt + 1) * 2048;
#pragma unroll
      for (int hh = 0; hh < 2; ++hh) {
        int f = t + hh * 256;
        kx[hh] = *(const f32x4*)(kb + (f >> 4) * 64 + (f & 15) * 4);
        vx[hh] = *(const f32x4*)(vb + (f >> 4) * 64 + (f & 15) * 4);
      }
    }
    BARRIER_LGKM();  // A: staged tile visible

    short8 afr[2][2];
#pragma unroll
    for (int nh1 = 0; nh1 < 2; ++nh1)
#pragma unroll
      for (int kk = 0; kk < 2; ++kk)
        afr[nh1][kk] = *(const short8*)&sX[nh1 * 16 + c][kk * 32 + g * 8];

    f32x4 acc1[2][4];
#pragma unroll
    for (int i = 0; i < 2; ++i)
#pragma unroll
      for (int j = 0; j < 4; ++j) acc1[i][j] = (f32x4){0.f, 0.f, 0.f, 0.f};
#pragma unroll
    for (int kk = 0; kk < 2; ++kk)
#pragma unroll
      for (int nh1 = 0; nh1 < 2; ++nh1)
#pragma unroll
        for (int mt = 0; mt < 4; ++mt)
          acc1[nh1][mt] = __builtin_amdgcn_mfma_f32_16x16x32_bf16(
              afr[nh1][kk], pfrag[mt][kk], acc1[nh1][mt], 0, 0, 0);

#pragma unroll
    for (int nh1 = 0; nh1 < 2; ++nh1)
#pragma unroll
      for (int mt = 0; mt < 4; ++mt) {
        int m = wid * 64 + mt * 16 + c;
        unsigned short wp[4];
#pragma unroll
        for (int r = 0; r < 4; ++r) {
          float dd = acc1[nh1][mt][r];
          gm = fmaxf(gm, dd);
          int n = nh1 * 16 + g * 4 + r;
          float w = EXP2F(dd - sDiag[n]);
          unsigned short wb = f2bf(w);
          kexpreg[mt] += bf2f(wb);
          wp[r] = wb;
        }
        us4 w4 = {wp[0], wp[1], wp[2], wp[3]};
        *(us4*)&sW[m][nh1 * 16 + g * 4] = w4;
      }

    // GEMM2 reads wave-private sW + post-barrier sVt: no barrier needed.
    short8 awt[4], bvv[4];
#pragma unroll
    for (int mt2 = 0; mt2 < 4; ++mt2)
      awt[mt2] = *(const short8*)&sW[wid * 64 + mt2 * 16 + c][g * 8];
#pragma unroll
    for (int et = 0; et < 4; ++et)
      bvv[et] = *(const short8*)&sVt[et * 16 + c][g * 8];
#pragma unroll
    for (int mt2 = 0; mt2 < 4; ++mt2)
#pragma unroll
      for (int et = 0; et < 4; ++et)
        ctx[mt2][et] = __builtin_amdgcn_mfma_f32_16x16x32_bf16(
            awt[mt2], bvv[et], ctx[mt2][et], 0, 0, 0);
  }

#pragma unroll
  for (int mt2 = 0; mt2 < 4; ++mt2)
#pragma unroll
    for (int et = 0; et < 4; ++et) {
      int m0 = wid * 64 + mt2 * 16 + g * 4;
      int e = et * 16 + c;
      size_t base = (((size_t)chunk * BH_ + bh) * 64 + e) * 256 + m0;
      *(f32x4*)(ctxp + base) = ctx[mt2][et];
    }
#pragma unroll
  for (int mt = 0; mt < 4; ++mt) {
    float s = kexpreg[mt];
    s += __shfl_xor(s, 16);
    s += __shfl_xor(s, 32);
    if (lane < 16)
      kexpp[((size_t)chunk * BH_ + bh) * 256 + wid * 64 + mt * 16 + lane] = s;
  }
  if (t < 64) sVsum[t] = 0.f;
  __syncthreads();
  atomicAdd(&sVsum[(t & 15) * 4 + 0], vsum0);
  atomicAdd(&sVsum[(t & 15) * 4 + 1], vsum1);
  atomicAdd(&sVsum[(t & 15) * 4 + 2], vsum2);
  atomicAdd(&sVsum[(t & 15) * 4 + 3], vsum3);
  __syncthreads();
  if (t < 64) vsump[((size_t)chunk * BH_ + bh) * 64 + t] = sVsum[t];

  gm = fmaxf(gm, __shfl_xor(gm, 1));
  gm = fmaxf(gm, __shfl_xor(gm, 2));
  gm = fmaxf(gm, __shfl_xor(gm, 4));
  gm = fmaxf(gm, __shfl_xor(gm, 8));
  gm = fmaxf(gm, __shfl_xor(gm, 16));
  gm = fmaxf(gm, __shfl_xor(gm, 32));
  if (lane == 0) sGm[wid] = gm;
  __syncthreads();
  if (t == 0) {
    float mm = fmaxf(fmaxf(sGm[0], sGm[1]), fmaxf(sGm[2], sGm[3]));
    atomicMax((int*)gmaxb, __float_as_int(mm));  // gmax2 > 0 in practice
  }
}

// ---------------------------------------------------------------------------
// Rescale: CTX = 2^-g*sum(ctx)+eps*vsum -> bf16 [bh][e][m];
//          KC  = 2^-g*sum(kexp)+eps*N   -> bf16 hi/lo split (f32 accuracy).
// ---------------------------------------------------------------------------
__global__ void perf_rescale(const float* __restrict__ ctxp,
                             const float* __restrict__ kexpp,
                             const float* __restrict__ vsump,
                             unsigned short* __restrict__ ctxt,
                             unsigned short* __restrict__ kchi,
                             unsigned short* __restrict__ kclo,
                             const unsigned int* __restrict__ gmaxb, int nchunk) {
  const int bh = blockIdx.x >> 3;
  const int es = blockIdx.x & 7;
  const int t = threadIdx.x;  // m
  const float gmax = __uint_as_float(*gmaxb);
  const float s = EXP2F(-gmax);
  if (es == 0) {
    float acc = 0.f;
    for (int cc = 0; cc < nchunk; ++cc)
      acc += kexpp[((size_t)cc * BH_ + bh) * 256 + t];
    float kcv = s * acc + EPSF * (float)N_;
    unsigned short hi = f2bf(kcv);
    kchi[bh * 256 + t] = hi;
    kclo[bh * 256 + t] = f2bf(kcv - bf2f(hi));
  }
  for (int e = es * 8; e < es * 8 + 8; ++e) {
    float vs = 0.f;
    for (int cc = 0; cc < nchunk; ++cc)
      vs += vsump[((size_t)cc * BH_ + bh) * 64 + e];
    float a2 = 0.f;
    for (int cc = 0; cc < nchunk; ++cc)
      a2 += ctxp[(((size_t)cc * BH_ + bh) * 64 + e) * 256 + t];
    ctxt[((size_t)bh * 64 + e) * 256 + t] = f2bf(s * a2 + EPSF * vs);
  }
}

// ---------------------------------------------------------------------------
// Q pass v2 — swapped GEMM1 (dd^T = P·X^T): each wave owns 16 n-rows and all
// 256 m. Rowmax/den/softmax wave-local; sQt wave-private (no barrier);
// 1 lgkm-only barrier per 64-row tile; sX double-buffered.
// ---------------------------------------------------------------------------
__global__ __launch_bounds__(256, 3)
void perf_qpass(const float* __restrict__ qp,
                const unsigned short* __restrict__ projb,
                const unsigned short* __restrict__ ctxt,
                const unsigned short* __restrict__ kchi,
                const unsigned short* __restrict__ kclo,
                float* __restrict__ outp) {
  const int bh = blockIdx.x & (BH_ - 1);
  const int chunk = blockIdx.x >> 7;  // 0..15, 256 rows
  const int t = threadIdx.x;
  const int wid = t >> 6;
  const int lane = t & 63;
  const int g = lane >> 4;
  const int c = lane & 15;

  __shared__ __align__(16) unsigned short sX[2][64][72];
  __shared__ __align__(16) unsigned short sQt[4][16][264];  // wave-private
  __shared__ float sDiag[2][64];

  const unsigned short* ctxb = ctxt + (size_t)bh * 64 * 256;
  const unsigned short* khib = kchi + bh * 256;
  const unsigned short* klob = kclo + bh * 256;
  const unsigned short* pb = projb + c * 64 + g * 8;  // + mt*1024 (+32 for kk=1)

  const float* qb0 = qp + ((size_t)bh * N_ + (size_t)chunk * 256) * 64;
  float* ob0 = outp + ((size_t)bh * N_ + (size_t)chunk * 256) * 64;

  f32x4 qx[4];
#pragma unroll
  for (int hh = 0; hh < 4; ++hh) {
    int f = t + hh * 256;
    qx[hh] = *(const f32x4*)(qb0 + (f >> 4) * 64 + (f & 15) * 4);
  }

  for (int nt = 0; nt < 4; ++nt) {
    const int buf = nt & 1;
    // ---- stage 64 rows into sX[buf] + diag ----
#pragma unroll
    for (int hh = 0; hh < 4; ++hh) {
      int row = (t >> 4) + 16 * hh;
      int c4 = t & 15;
      f32x4 x = qx[hh];
      float ss = x[0] * x[0] + x[1] * x[1] + x[2] * x[2] + x[3] * x[3];
      ss += __shfl_xor(ss, 1);
      ss += __shfl_xor(ss, 2);
      ss += __shfl_xor(ss, 4);
      ss += __shfl_xor(ss, 8);
      if (c4 == 0) sDiag[buf][row] = DIAGL * ss;
      *(us4*)&sX[buf][row][c4 * 4] = cvt4(x);
    }
    if (nt + 1 < 4) {  // prefetch: survives the lgkm-only barrier
      const float* qb = qb0 + (nt + 1) * 4096;
#pragma unroll
      for (int hh = 0; hh < 4; ++hh) {
        int f = t + hh * 256;
        qx[hh] = *(const f32x4*)(qb + (f >> 4) * 64 + (f & 15) * 4);
      }
    }
    BARRIER_LGKM();  // staged tile visible; only barrier in the loop

    // ---- GEMM1: dd^T[256m x 16n] = P · X^T (wave's n = wid*16 + c) ----
    short8 xb[2];
#pragma unroll
    for (int kk = 0; kk < 2; ++kk)
      xb[kk] = *(const short8*)&sX[buf][wid * 16 + c][kk * 32 + g * 8];

    f32x4 acc1[16];
#pragma unroll
    for (int mt = 0; mt < 16; ++mt) acc1[mt] = (f32x4){0.f, 0.f, 0.f, 0.f};
#pragma unroll
    for (int mt = 0; mt < 16; ++mt) {
      short8 p0 = *(const short8*)(pb + mt * 1024);
      short8 p1 = *(const short8*)(pb + mt * 1024 + 32);
      acc1[mt] = __builtin_amdgcn_mfma_f32_16x16x32_bf16(p0, xb[0], acc1[mt], 0, 0, 0);
      acc1[mt] = __builtin_amdgcn_mfma_f32_16x16x32_bf16(p1, xb[1], acc1[mt], 0, 0, 0);
    }
    // lane (g,c): m = mt*16 + g*4 + r, n = wid*16 + c.

    // ---- rowmax over m: in-lane (64 vals) + 2 shfl across g ----
    float mx = acc1[0][0];
#pragma unroll
    for (int mt = 0; mt < 16; ++mt)
#pragma unroll
      for (int r = 0; r < 4; ++r) mx = fmaxf(mx, acc1[mt][r]);
    mx = fmaxf(mx, __shfl_xor(mx, 16));
    mx = fmaxf(mx, __shfl_xor(mx, 32));
    float base = sDiag[buf][wid * 16 + c] + mx;

    // ---- qt = exp2(dd - base) + eps -> bf16 pairs -> wave-private sQt ----
#pragma unroll
    for (int mt = 0; mt < 16; ++mt) {
      float q0 = EXP2F(acc1[mt][0] - base) + EPSF;
      float q1 = EXP2F(acc1[mt][1] - base) + EPSF;
      float q2 = EXP2F(acc1[mt][2] - base) + EPSF;
      float q3 = EXP2F(acc1[mt][3] - base) + EPSF;
      unsigned int d0 = pk2bf(q0, q1);
      unsigned int d1 = pk2bf(q2, q3);
      *(unsigned int*)&sQt[wid][c][mt * 16 + g * 4] = d0;
      *(unsigned int*)&sQt[wid][c][mt * 16 + g * 4 + 2] = d1;
    }

    // ---- GEMM2: out[16n x 64e] = qt · CTX^T ; et=4 carries kc hi/lo ----
    f32x4 acc2[5];
#pragma unroll
    for (int et = 0; et < 5; ++et) acc2[et] = (f32x4){0.f, 0.f, 0.f, 0.f};
    const short8 bz = {0, 0, 0, 0, 0, 0, 0, 0};
#pragma unroll
    for (int kc2 = 0; kc2 < 8; ++kc2) {
      short8 a = *(const short8*)&sQt[wid][c][kc2 * 32 + g * 8];  // own region
#pragma unroll
      for (int et = 0; et < 4; ++et) {
        short8 b = *(const short8*)&ctxb[(et * 16 + c) * 256 + kc2 * 32 + g * 8];
        acc2[et] = __builtin_amdgcn_mfma_f32_16x16x32_bf16(a, b, acc2[et], 0, 0, 0);
      }
      short8 hi8 = *(const short8*)&khib[kc2 * 32 + g * 8];
      short8 lo8 = *(const short8*)&klob[kc2 * 32 + g * 8];
      short8 bden = (c == 0) ? hi8 : ((c == 1) ? lo8 : bz);
      acc2[4] = __builtin_amdgcn_mfma_f32_16x16x32_bf16(a, bden, acc2[4], 0, 0, 0);
    }

    // ---- den broadcast + divide + store (lane holds rows g*4+r, e=et*16+c)
#pragma unroll
    for (int r = 0; r < 4; ++r) {
      float den = __shfl(acc2[4][r], g * 16) + __shfl(acc2[4][r], g * 16 + 1);
      float rinv = 1.0f / den;
      int n = nt * 64 + wid * 16 + g * 4 + r;
#pragma unroll
      for (int et = 0; et < 4; ++et)
        ob0[(size_t)n * 64 + et * 16 + c] = acc2[et][r] * rinv;
    }
    // no trailing barrier: sX double-buffered; sQt wave-private; next
    // iteration's BARRIER_LGKM orders everything else.
  }
}

extern "C" void kernel_launch(void* const* d_in, const int* in_sizes, int n_in,
                              void* d_out, int out_size, void* d_ws, size_t ws_size,
                              hipStream_t stream) {
  (void)in_sizes; (void)n_in; (void)out_size;
  const float* qp = (const float*)d_in[0];
  const float* kp = (const float*)d_in[1];
  const float* vp = (const float*)d_in[2];
  const float* proj = (const float*)d_in[3];
  float* outp = (float*)d_out;

  int nchunk = 8;
  while (nchunk > 1) {
    size_t fl = 64 + (size_t)nchunk * (2097152 + 32768 + 8192);
    size_t needed = fl * 4 + (size_t)(2097152 + 32768 + 32768 + 16384) * 2;
    if (needed <= ws_size) break;
    nchunk >>= 1;
  }

  float* wsf = (float*)d_ws;
  unsigned int* gmaxb = (unsigned int*)d_ws;
  float* ctxp = wsf + 64;
  float* kexpp = ctxp + (size_t)nchunk * 128 * 64 * 256;
  float* vsump = kexpp + (size_t)nchunk * 128 * 256;
  unsigned short* ctxt = (unsigned short*)(vsump + (size_t)nchunk * 128 * 64);
  unsigned short* kchi = ctxt + (size_t)128 * 64 * 256;
  unsigned short* kclo = kchi + 128 * 256;
  unsigned short* projb = kclo + 128 * 256;

  hipMemsetAsync(d_ws, 0, 16, stream);
  hipLaunchKernelGGL(perf_prep, dim3(64), dim3(256), 0, stream, proj, projb);
  hipLaunchKernelGGL(perf_kpass, dim3(128 * nchunk), dim3(256), 0, stream,
                     kp, vp, proj, ctxp, kexpp, vsump, gmaxb, nchunk);
  hipLaunchKernelGGL(perf_rescale, dim3(128 * 8), dim3(256), 0, stream,
                     ctxp, kexpp, vsump, ctxt, kchi, kclo, gmaxb, nchunk);
  hipLaunchKernelGGL(perf_qpass, dim3(128 * 16), dim3(256), 0, stream,
                     qp, projb, ctxt, kchi, kclo, outp);
}

// Round 5
// 416.708 us; speedup vs baseline: 1.2777x; 1.2777x over previous
//
#include <hip/hip_runtime.h>
#include <hip/hip_bf16.h>

typedef __attribute__((ext_vector_type(4))) float f32x4;
typedef __attribute__((ext_vector_type(8))) short short8;
typedef __attribute__((ext_vector_type(4))) unsigned short us4;

#define BH_ 128
#define N_ 4096
#define LOG2E 1.4426950408889634f
#define NORML (0.35355339059327373f * LOG2E)  // d^-0.25 * log2(e) folded into P
#define DIAGL (0.0625f * LOG2E)               // 0.5*d^-0.5 * log2(e)
#define EPSF 1e-4f

#if __has_builtin(__builtin_amdgcn_exp2f)
#define EXP2F(x) __builtin_amdgcn_exp2f(x)
#else
#define EXP2F(x) exp2f(x)
#endif

// LDS-only barrier: orders ds_write/ds_read across waves WITHOUT draining
// vmcnt — in-flight global prefetch loads survive the barrier (T4).
#define BARRIER_LGKM() asm volatile("s_waitcnt lgkmcnt(0)\ns_barrier" ::: "memory")

static __device__ __forceinline__ unsigned short f2bf(float f) {
  return __bfloat16_as_ushort(__float2bfloat16(f));  // RNE, HW cvt
}
static __device__ __forceinline__ float bf2f(unsigned short s) {
  return __uint_as_float(((unsigned int)s) << 16);
}
static __device__ __forceinline__ us4 cvt4(f32x4 x) {
  us4 r;
  r[0] = f2bf(x[0]); r[1] = f2bf(x[1]); r[2] = f2bf(x[2]); r[3] = f2bf(x[3]);
  return r;
}
static __device__ __forceinline__ unsigned int pk2bf(float lo, float hi) {
  unsigned int r;
  asm("v_cvt_pk_bf16_f32 %0, %1, %2" : "=v"(r) : "v"(lo), "v"(hi));
  return r;
}

// ---------------------------------------------------------------------------
// prep: projection -> bf16 with NORML folded (consumed by qpass GEMM1).
// ---------------------------------------------------------------------------
__global__ void perf_prep(const float* __restrict__ proj,
                          unsigned short* __restrict__ projb) {
  int i = blockIdx.x * 256 + threadIdx.x;  // 16384 total
  projb[i] = f2bf(proj[i] * NORML);
}

// ---------------------------------------------------------------------------
// K pass (log2 domain) — lgkm-only barriers so the K/V register prefetch
// stays in flight across the whole tile compute.
// RULE (r2/r4 post-mortems): this family needs __launch_bounds__(256,2);
// tighter min-wave bounds cause VGPR spills -> scratch-bound (FETCH/WRITE
// inflation, MfmaUtil collapse).
// ---------------------------------------------------------------------------
__global__ __launch_bounds__(256, 2)
void perf_kpass(const float* __restrict__ kp, const float* __restrict__ vp,
                const float* __restrict__ proj, float* __restrict__ ctxp,
                float* __restrict__ kexpp, float* __restrict__ vsump,
                unsigned int* __restrict__ gmaxb, int nchunk) {
  const int bh = blockIdx.x & (BH_ - 1);
  const int chunk = blockIdx.x >> 7;
  const int chunkrows = N_ / nchunk;
  const int tiles = chunkrows >> 5;
  const int t = threadIdx.x;
  const int wid = t >> 6;
  const int lane = t & 63;
  const int g = lane >> 4;
  const int c = lane & 15;

  __shared__ __align__(16) unsigned short sX[32][72];
  __shared__ __align__(16) unsigned short sVt[64][40];
  __shared__ __align__(16) unsigned short sW[256][40];
  __shared__ float sDiag[32];
  __shared__ float sVsum[64];
  __shared__ float sGm[4];

  short8 pfrag[4][2];
#pragma unroll
  for (int mt = 0; mt < 4; ++mt)
#pragma unroll
    for (int kk = 0; kk < 2; ++kk) {
      const float* src = proj + (wid * 64 + mt * 16 + c) * 64 + kk * 32 + g * 8;
      short8 v;
#pragma unroll
      for (int j = 0; j < 8; ++j) v[j] = (short)f2bf(src[j] * NORML);
      pfrag[mt][kk] = v;
    }

  f32x4 ctx[4][4];
#pragma unroll
  for (int i = 0; i < 4; ++i)
#pragma unroll
    for (int j = 0; j < 4; ++j) ctx[i][j] = (f32x4){0.f, 0.f, 0.f, 0.f};

  float kexpreg[4] = {0.f, 0.f, 0.f, 0.f};
  float vsum0 = 0.f, vsum1 = 0.f, vsum2 = 0.f, vsum3 = 0.f;
  float gm = -1e30f;

  const float* kb0 = kp + ((size_t)bh * N_ + (size_t)chunk * chunkrows) * 64;
  const float* vb0 = vp + ((size_t)bh * N_ + (size_t)chunk * chunkrows) * 64;

  f32x4 kx[2], vx[2];
#pragma unroll
  for (int hh = 0; hh < 2; ++hh) {
    int f = t + hh * 256;
    kx[hh] = *(const f32x4*)(kb0 + (f >> 4) * 64 + (f & 15) * 4);
    vx[hh] = *(const f32x4*)(vb0 + (f >> 4) * 64 + (f & 15) * 4);
  }

  for (int nt = 0; nt < tiles; ++nt) {
    BARRIER_LGKM();  // S: prev tile's ds_reads done before overwrite
#pragma unroll
    for (int hh = 0; hh < 2; ++hh) {
      int f = t + hh * 256;
      int row = f >> 4;
      int c4 = f & 15;
      f32x4 x = kx[hh];
      float ss = x[0] * x[0] + x[1] * x[1] + x[2] * x[2] + x[3] * x[3];
      ss += __shfl_xor(ss, 1);
      ss += __shfl_xor(ss, 2);
      ss += __shfl_xor(ss, 4);
      ss += __shfl_xor(ss, 8);
      if (c4 == 0) sDiag[row] = DIAGL * ss;
      *(us4*)&sX[row][c4 * 4] = cvt4(x);
      f32x4 vv = vx[hh];
      vsum0 += vv[0]; vsum1 += vv[1]; vsum2 += vv[2]; vsum3 += vv[3];
#pragma unroll
      for (int jj = 0; jj < 4; ++jj) {
        int j = (jj + t) & 3;  // rotate to spread banks
        float val = (j == 0) ? vv[0] : (j == 1) ? vv[1] : (j == 2) ? vv[2] : vv[3];
        sVt[c4 * 4 + j][row] = f2bf(val);
      }
    }
    if (nt + 1 < tiles) {  // prefetch survives the lgkm-only barrier below
      const float* kb = kb0 + (nt + 1) * 2048;
      const float* vb = vb0 + (nt + 1) * 2048;
#pragma unroll
      for (int hh = 0; hh < 2; ++hh) {
        int f = t + hh * 256;
        kx[hh] = *(const f32x4*)(kb + (f >> 4) * 64 + (f & 15) * 4);
        vx[hh] = *(const f32x4*)(vb + (f >> 4) * 64 + (f & 15) * 4);
      }
    }
    BARRIER_LGKM();  // A: staged tile visible

    short8 afr[2][2];
#pragma unroll
    for (int nh1 = 0; nh1 < 2; ++nh1)
#pragma unroll
      for (int kk = 0; kk < 2; ++kk)
        afr[nh1][kk] = *(const short8*)&sX[nh1 * 16 + c][kk * 32 + g * 8];

    f32x4 acc1[2][4];
#pragma unroll
    for (int i = 0; i < 2; ++i)
#pragma unroll
      for (int j = 0; j < 4; ++j) acc1[i][j] = (f32x4){0.f, 0.f, 0.f, 0.f};
#pragma unroll
    for (int kk = 0; kk < 2; ++kk)
#pragma unroll
      for (int nh1 = 0; nh1 < 2; ++nh1)
#pragma unroll
        for (int mt = 0; mt < 4; ++mt)
          acc1[nh1][mt] = __builtin_amdgcn_mfma_f32_16x16x32_bf16(
              afr[nh1][kk], pfrag[mt][kk], acc1[nh1][mt], 0, 0, 0);

#pragma unroll
    for (int nh1 = 0; nh1 < 2; ++nh1)
#pragma unroll
      for (int mt = 0; mt < 4; ++mt) {
        int m = wid * 64 + mt * 16 + c;
        unsigned short wp[4];
#pragma unroll
        for (int r = 0; r < 4; ++r) {
          float dd = acc1[nh1][mt][r];
          gm = fmaxf(gm, dd);
          int n = nh1 * 16 + g * 4 + r;
          float w = EXP2F(dd - sDiag[n]);
          unsigned short wb = f2bf(w);
          kexpreg[mt] += bf2f(wb);
          wp[r] = wb;
        }
        us4 w4 = {wp[0], wp[1], wp[2], wp[3]};
        *(us4*)&sW[m][nh1 * 16 + g * 4] = w4;
      }

    // GEMM2 reads wave-private sW + post-barrier sVt: no barrier needed.
    short8 awt[4], bvv[4];
#pragma unroll
    for (int mt2 = 0; mt2 < 4; ++mt2)
      awt[mt2] = *(const short8*)&sW[wid * 64 + mt2 * 16 + c][g * 8];
#pragma unroll
    for (int et = 0; et < 4; ++et)
      bvv[et] = *(const short8*)&sVt[et * 16 + c][g * 8];
#pragma unroll
    for (int mt2 = 0; mt2 < 4; ++mt2)
#pragma unroll
      for (int et = 0; et < 4; ++et)
        ctx[mt2][et] = __builtin_amdgcn_mfma_f32_16x16x32_bf16(
            awt[mt2], bvv[et], ctx[mt2][et], 0, 0, 0);
  }

#pragma unroll
  for (int mt2 = 0; mt2 < 4; ++mt2)
#pragma unroll
    for (int et = 0; et < 4; ++et) {
      int m0 = wid * 64 + mt2 * 16 + g * 4;
      int e = et * 16 + c;
      size_t base = (((size_t)chunk * BH_ + bh) * 64 + e) * 256 + m0;
      *(f32x4*)(ctxp + base) = ctx[mt2][et];
    }
#pragma unroll
  for (int mt = 0; mt < 4; ++mt) {
    float s = kexpreg[mt];
    s += __shfl_xor(s, 16);
    s += __shfl_xor(s, 32);
    if (lane < 16)
      kexpp[((size_t)chunk * BH_ + bh) * 256 + wid * 64 + mt * 16 + lane] = s;
  }
  if (t < 64) sVsum[t] = 0.f;
  __syncthreads();
  atomicAdd(&sVsum[(t & 15) * 4 + 0], vsum0);
  atomicAdd(&sVsum[(t & 15) * 4 + 1], vsum1);
  atomicAdd(&sVsum[(t & 15) * 4 + 2], vsum2);
  atomicAdd(&sVsum[(t & 15) * 4 + 3], vsum3);
  __syncthreads();
  if (t < 64) vsump[((size_t)chunk * BH_ + bh) * 64 + t] = sVsum[t];

  gm = fmaxf(gm, __shfl_xor(gm, 1));
  gm = fmaxf(gm, __shfl_xor(gm, 2));
  gm = fmaxf(gm, __shfl_xor(gm, 4));
  gm = fmaxf(gm, __shfl_xor(gm, 8));
  gm = fmaxf(gm, __shfl_xor(gm, 16));
  gm = fmaxf(gm, __shfl_xor(gm, 32));
  if (lane == 0) sGm[wid] = gm;
  __syncthreads();
  if (t == 0) {
    float mm = fmaxf(fmaxf(sGm[0], sGm[1]), fmaxf(sGm[2], sGm[3]));
    atomicMax((int*)gmaxb, __float_as_int(mm));  // gmax2 > 0 in practice
  }
}

// ---------------------------------------------------------------------------
// Rescale: CTX = 2^-g*sum(ctx)+eps*vsum -> bf16 [bh][e][m];
//          KC  = 2^-g*sum(kexp)+eps*N   -> bf16 hi/lo split (f32 accuracy).
// ---------------------------------------------------------------------------
__global__ void perf_rescale(const float* __restrict__ ctxp,
                             const float* __restrict__ kexpp,
                             const float* __restrict__ vsump,
                             unsigned short* __restrict__ ctxt,
                             unsigned short* __restrict__ kchi,
                             unsigned short* __restrict__ kclo,
                             const unsigned int* __restrict__ gmaxb, int nchunk) {
  const int bh = blockIdx.x >> 3;
  const int es = blockIdx.x & 7;
  const int t = threadIdx.x;  // m
  const float gmax = __uint_as_float(*gmaxb);
  const float s = EXP2F(-gmax);
  if (es == 0) {
    float acc = 0.f;
    for (int cc = 0; cc < nchunk; ++cc)
      acc += kexpp[((size_t)cc * BH_ + bh) * 256 + t];
    float kcv = s * acc + EPSF * (float)N_;
    unsigned short hi = f2bf(kcv);
    kchi[bh * 256 + t] = hi;
    kclo[bh * 256 + t] = f2bf(kcv - bf2f(hi));
  }
  for (int e = es * 8; e < es * 8 + 8; ++e) {
    float vs = 0.f;
    for (int cc = 0; cc < nchunk; ++cc)
      vs += vsump[((size_t)cc * BH_ + bh) * 64 + e];
    float a2 = 0.f;
    for (int cc = 0; cc < nchunk; ++cc)
      a2 += ctxp[(((size_t)cc * BH_ + bh) * 64 + e) * 256 + t];
    ctxt[((size_t)bh * 64 + e) * 256 + t] = f2bf(s * a2 + EPSF * vs);
  }
}

// ---------------------------------------------------------------------------
// Q pass v2 — swapped GEMM1 (dd^T = P·X^T): each wave owns 16 n-rows and all
// 256 m. Rowmax/den/softmax wave-local; sQt wave-private (no barrier);
// 1 lgkm-only barrier per 64-row tile; sX double-buffered.
// __launch_bounds__(256,2): (256,3) spilled acc1[16]=64 VGPRs (r4: WRITE
// 131->254MB scratch, FETCH 75->320MB, dur 415us). Family rule: (256,2).
// ---------------------------------------------------------------------------
__global__ __launch_bounds__(256, 2)
void perf_qpass(const float* __restrict__ qp,
                const unsigned short* __restrict__ projb,
                const unsigned short* __restrict__ ctxt,
                const unsigned short* __restrict__ kchi,
                const unsigned short* __restrict__ kclo,
                float* __restrict__ outp) {
  const int bh = blockIdx.x & (BH_ - 1);
  const int chunk = blockIdx.x >> 7;  // 0..15, 256 rows
  const int t = threadIdx.x;
  const int wid = t >> 6;
  const int lane = t & 63;
  const int g = lane >> 4;
  const int c = lane & 15;

  __shared__ __align__(16) unsigned short sX[2][64][72];
  __shared__ __align__(16) unsigned short sQt[4][16][264];  // wave-private
  __shared__ float sDiag[2][64];

  const unsigned short* ctxb = ctxt + (size_t)bh * 64 * 256;
  const unsigned short* khib = kchi + bh * 256;
  const unsigned short* klob = kclo + bh * 256;
  const unsigned short* pb = projb + c * 64 + g * 8;  // + mt*1024 (+32 for kk=1)

  const float* qb0 = qp + ((size_t)bh * N_ + (size_t)chunk * 256) * 64;
  float* ob0 = outp + ((size_t)bh * N_ + (size_t)chunk * 256) * 64;

  f32x4 qx[4];
#pragma unroll
  for (int hh = 0; hh < 4; ++hh) {
    int f = t + hh * 256;
    qx[hh] = *(const f32x4*)(qb0 + (f >> 4) * 64 + (f & 15) * 4);
  }

  for (int nt = 0; nt < 4; ++nt) {
    const int buf = nt & 1;
    // ---- stage 64 rows into sX[buf] + diag ----
#pragma unroll
    for (int hh = 0; hh < 4; ++hh) {
      int row = (t >> 4) + 16 * hh;
      int c4 = t & 15;
      f32x4 x = qx[hh];
      float ss = x[0] * x[0] + x[1] * x[1] + x[2] * x[2] + x[3] * x[3];
      ss += __shfl_xor(ss, 1);
      ss += __shfl_xor(ss, 2);
      ss += __shfl_xor(ss, 4);
      ss += __shfl_xor(ss, 8);
      if (c4 == 0) sDiag[buf][row] = DIAGL * ss;
      *(us4*)&sX[buf][row][c4 * 4] = cvt4(x);
    }
    if (nt + 1 < 4) {  // prefetch: survives the lgkm-only barrier
      const float* qb = qb0 + (nt + 1) * 4096;
#pragma unroll
      for (int hh = 0; hh < 4; ++hh) {
        int f = t + hh * 256;
        qx[hh] = *(const f32x4*)(qb + (f >> 4) * 64 + (f & 15) * 4);
      }
    }
    BARRIER_LGKM();  // staged tile visible; only barrier in the loop

    // ---- GEMM1: dd^T[256m x 16n] = P · X^T (wave's n = wid*16 + c) ----
    short8 xb[2];
#pragma unroll
    for (int kk = 0; kk < 2; ++kk)
      xb[kk] = *(const short8*)&sX[buf][wid * 16 + c][kk * 32 + g * 8];

    f32x4 acc1[16];
#pragma unroll
    for (int mt = 0; mt < 16; ++mt) acc1[mt] = (f32x4){0.f, 0.f, 0.f, 0.f};
#pragma unroll
    for (int mt = 0; mt < 16; ++mt) {
      short8 p0 = *(const short8*)(pb + mt * 1024);
      short8 p1 = *(const short8*)(pb + mt * 1024 + 32);
      acc1[mt] = __builtin_amdgcn_mfma_f32_16x16x32_bf16(p0, xb[0], acc1[mt], 0, 0, 0);
      acc1[mt] = __builtin_amdgcn_mfma_f32_16x16x32_bf16(p1, xb[1], acc1[mt], 0, 0, 0);
    }
    // lane (g,c): m = mt*16 + g*4 + r, n = wid*16 + c.

    // ---- rowmax over m: in-lane (64 vals) + 2 shfl across g ----
    float mx = acc1[0][0];
#pragma unroll
    for (int mt = 0; mt < 16; ++mt)
#pragma unroll
      for (int r = 0; r < 4; ++r) mx = fmaxf(mx, acc1[mt][r]);
    mx = fmaxf(mx, __shfl_xor(mx, 16));
    mx = fmaxf(mx, __shfl_xor(mx, 32));
    float base = sDiag[buf][wid * 16 + c] + mx;

    // ---- qt = exp2(dd - base) + eps -> bf16 pairs -> wave-private sQt ----
#pragma unroll
    for (int mt = 0; mt < 16; ++mt) {
      float q0 = EXP2F(acc1[mt][0] - base) + EPSF;
      float q1 = EXP2F(acc1[mt][1] - base) + EPSF;
      float q2 = EXP2F(acc1[mt][2] - base) + EPSF;
      float q3 = EXP2F(acc1[mt][3] - base) + EPSF;
      unsigned int d0 = pk2bf(q0, q1);
      unsigned int d1 = pk2bf(q2, q3);
      *(unsigned int*)&sQt[wid][c][mt * 16 + g * 4] = d0;
      *(unsigned int*)&sQt[wid][c][mt * 16 + g * 4 + 2] = d1;
    }

    // ---- GEMM2: out[16n x 64e] = qt · CTX^T ; et=4 carries kc hi/lo ----
    f32x4 acc2[5];
#pragma unroll
    for (int et = 0; et < 5; ++et) acc2[et] = (f32x4){0.f, 0.f, 0.f, 0.f};
    const short8 bz = {0, 0, 0, 0, 0, 0, 0, 0};
#pragma unroll
    for (int kc2 = 0; kc2 < 8; ++kc2) {
      short8 a = *(const short8*)&sQt[wid][c][kc2 * 32 + g * 8];  // own region
#pragma unroll
      for (int et = 0; et < 4; ++et) {
        short8 b = *(const short8*)&ctxb[(et * 16 + c) * 256 + kc2 * 32 + g * 8];
        acc2[et] = __builtin_amdgcn_mfma_f32_16x16x32_bf16(a, b, acc2[et], 0, 0, 0);
      }
      short8 hi8 = *(const short8*)&khib[kc2 * 32 + g * 8];
      short8 lo8 = *(const short8*)&klob[kc2 * 32 + g * 8];
      short8 bden = (c == 0) ? hi8 : ((c == 1) ? lo8 : bz);
      acc2[4] = __builtin_amdgcn_mfma_f32_16x16x32_bf16(a, bden, acc2[4], 0, 0, 0);
    }

    // ---- den broadcast + divide + store (lane holds rows g*4+r, e=et*16+c)
#pragma unroll
    for (int r = 0; r < 4; ++r) {
      float den = __shfl(acc2[4][r], g * 16) + __shfl(acc2[4][r], g * 16 + 1);
      float rinv = 1.0f / den;
      int n = nt * 64 + wid * 16 + g * 4 + r;
#pragma unroll
      for (int et = 0; et < 4; ++et)
        ob0[(size_t)n * 64 + et * 16 + c] = acc2[et][r] * rinv;
    }
    // no trailing barrier: sX double-buffered; sQt wave-private; next
    // iteration's BARRIER_LGKM orders everything else.
  }
}

extern "C" void kernel_launch(void* const* d_in, const int* in_sizes, int n_in,
                              void* d_out, int out_size, void* d_ws, size_t ws_size,
                              hipStream_t stream) {
  (void)in_sizes; (void)n_in; (void)out_size;
  const float* qp = (const float*)d_in[0];
  const float* kp = (const float*)d_in[1];
  const float* vp = (const float*)d_in[2];
  const float* proj = (const float*)d_in[3];
  float* outp = (float*)d_out;

  int nchunk = 8;
  while (nchunk > 1) {
    size_t fl = 64 + (size_t)nchunk * (2097152 + 32768 + 8192);
    size_t needed = fl * 4 + (size_t)(2097152 + 32768 + 32768 + 16384) * 2;
    if (needed <= ws_size) break;
    nchunk >>= 1;
  }

  float* wsf = (float*)d_ws;
  unsigned int* gmaxb = (unsigned int*)d_ws;
  float* ctxp = wsf + 64;
  float* kexpp = ctxp + (size_t)nchunk * 128 * 64 * 256;
  float* vsump = kexpp + (size_t)nchunk * 128 * 256;
  unsigned short* ctxt = (unsigned short*)(vsump + (size_t)nchunk * 128 * 64);
  unsigned short* kchi = ctxt + (size_t)128 * 64 * 256;
  unsigned short* kclo = kchi + 128 * 256;
  unsigned short* projb = kclo + 128 * 256;

  hipMemsetAsync(d_ws, 0, 16, stream);
  hipLaunchKernelGGL(perf_prep, dim3(64), dim3(256), 0, stream, proj, projb);
  hipLaunchKernelGGL(perf_kpass, dim3(128 * nchunk), dim3(256), 0, stream,
                     kp, vp, proj, ctxp, kexpp, vsump, gmaxb, nchunk);
  hipLaunchKernelGGL(perf_rescale, dim3(128 * 8), dim3(256), 0, stream,
                     ctxp, kexpp, vsump, ctxt, kchi, kclo, gmaxb, nchunk);
  hipLaunchKernelGGL(perf_qpass, dim3(128 * 16), dim3(256), 0, stream,
                     qp, projb, ctxt, kchi, kclo, outp);
}

// Round 6
// 410.163 us; speedup vs baseline: 1.2981x; 1.0160x over previous
//
#include <hip/hip_runtime.h>
#include <hip/hip_bf16.h>

typedef __attribute__((ext_vector_type(4))) float f32x4;
typedef __attribute__((ext_vector_type(8))) short short8;
typedef __attribute__((ext_vector_type(4))) unsigned short us4;

#define BH_ 128
#define N_ 4096
#define LOG2E 1.4426950408889634f
#define NORML (0.35355339059327373f * LOG2E)  // d^-0.25 * log2(e) folded into P
#define DIAGL (0.0625f * LOG2E)               // 0.5*d^-0.5 * log2(e)
#define EPSF 1e-4f

#if __has_builtin(__builtin_amdgcn_exp2f)
#define EXP2F(x) __builtin_amdgcn_exp2f(x)
#else
#define EXP2F(x) exp2f(x)
#endif

// LDS-only barrier: orders ds_write/ds_read across waves WITHOUT draining
// vmcnt — in-flight global prefetch loads survive the barrier (T4).
#define BARRIER_LGKM() asm volatile("s_waitcnt lgkmcnt(0)\ns_barrier" ::: "memory")

static __device__ __forceinline__ unsigned short f2bf(float f) {
  return __bfloat16_as_ushort(__float2bfloat16(f));  // RNE, HW cvt
}
static __device__ __forceinline__ float bf2f(unsigned short s) {
  return __uint_as_float(((unsigned int)s) << 16);
}
static __device__ __forceinline__ us4 cvt4(f32x4 x) {
  us4 r;
  r[0] = f2bf(x[0]); r[1] = f2bf(x[1]); r[2] = f2bf(x[2]); r[3] = f2bf(x[3]);
  return r;
}
static __device__ __forceinline__ unsigned int pk2bf(float lo, float hi) {
  unsigned int r;
  asm("v_cvt_pk_bf16_f32 %0, %1, %2" : "=v"(r) : "v"(lo), "v"(hi));
  return r;
}

// ---------------------------------------------------------------------------
// prep: projection -> bf16 with NORML folded (consumed by qpass GEMM1).
// ---------------------------------------------------------------------------
__global__ void perf_prep(const float* __restrict__ proj,
                          unsigned short* __restrict__ projb) {
  int i = blockIdx.x * 256 + threadIdx.x;  // 16384 total
  projb[i] = f2bf(proj[i] * NORML);
}

// ---------------------------------------------------------------------------
// K pass (log2 domain) — lgkm-only barriers so the K/V register prefetch
// stays in flight across the whole tile compute.
// RULE (r2/r4 post-mortems): __launch_bounds__(256,2); tighter min-wave
// bounds spill (FETCH/WRITE inflation, MfmaUtil collapse).
// ---------------------------------------------------------------------------
__global__ __launch_bounds__(256, 2)
void perf_kpass(const float* __restrict__ kp, const float* __restrict__ vp,
                const float* __restrict__ proj, float* __restrict__ ctxp,
                float* __restrict__ kexpp, float* __restrict__ vsump,
                unsigned int* __restrict__ gmaxb, int nchunk) {
  const int bh = blockIdx.x & (BH_ - 1);
  const int chunk = blockIdx.x >> 7;
  const int chunkrows = N_ / nchunk;
  const int tiles = chunkrows >> 5;
  const int t = threadIdx.x;
  const int wid = t >> 6;
  const int lane = t & 63;
  const int g = lane >> 4;
  const int c = lane & 15;

  __shared__ __align__(16) unsigned short sX[32][72];
  __shared__ __align__(16) unsigned short sVt[64][40];
  __shared__ __align__(16) unsigned short sW[256][40];
  __shared__ float sDiag[32];
  __shared__ float sVsum[64];
  __shared__ float sGm[4];

  short8 pfrag[4][2];
#pragma unroll
  for (int mt = 0; mt < 4; ++mt)
#pragma unroll
    for (int kk = 0; kk < 2; ++kk) {
      const float* src = proj + (wid * 64 + mt * 16 + c) * 64 + kk * 32 + g * 8;
      short8 v;
#pragma unroll
      for (int j = 0; j < 8; ++j) v[j] = (short)f2bf(src[j] * NORML);
      pfrag[mt][kk] = v;
    }

  f32x4 ctx[4][4];
#pragma unroll
  for (int i = 0; i < 4; ++i)
#pragma unroll
    for (int j = 0; j < 4; ++j) ctx[i][j] = (f32x4){0.f, 0.f, 0.f, 0.f};

  float kexpreg[4] = {0.f, 0.f, 0.f, 0.f};
  float vsum0 = 0.f, vsum1 = 0.f, vsum2 = 0.f, vsum3 = 0.f;
  float gm = -1e30f;

  const float* kb0 = kp + ((size_t)bh * N_ + (size_t)chunk * chunkrows) * 64;
  const float* vb0 = vp + ((size_t)bh * N_ + (size_t)chunk * chunkrows) * 64;

  f32x4 kx[2], vx[2];
#pragma unroll
  for (int hh = 0; hh < 2; ++hh) {
    int f = t + hh * 256;
    kx[hh] = *(const f32x4*)(kb0 + (f >> 4) * 64 + (f & 15) * 4);
    vx[hh] = *(const f32x4*)(vb0 + (f >> 4) * 64 + (f & 15) * 4);
  }

  for (int nt = 0; nt < tiles; ++nt) {
    BARRIER_LGKM();  // S: prev tile's ds_reads done before overwrite
#pragma unroll
    for (int hh = 0; hh < 2; ++hh) {
      int f = t + hh * 256;
      int row = f >> 4;
      int c4 = f & 15;
      f32x4 x = kx[hh];
      float ss = x[0] * x[0] + x[1] * x[1] + x[2] * x[2] + x[3] * x[3];
      ss += __shfl_xor(ss, 1);
      ss += __shfl_xor(ss, 2);
      ss += __shfl_xor(ss, 4);
      ss += __shfl_xor(ss, 8);
      if (c4 == 0) sDiag[row] = DIAGL * ss;
      *(us4*)&sX[row][c4 * 4] = cvt4(x);
      f32x4 vv = vx[hh];
      vsum0 += vv[0]; vsum1 += vv[1]; vsum2 += vv[2]; vsum3 += vv[3];
#pragma unroll
      for (int jj = 0; jj < 4; ++jj) {
        int j = (jj + t) & 3;  // rotate to spread banks
        float val = (j == 0) ? vv[0] : (j == 1) ? vv[1] : (j == 2) ? vv[2] : vv[3];
        sVt[c4 * 4 + j][row] = f2bf(val);
      }
    }
    if (nt + 1 < tiles) {  // prefetch survives the lgkm-only barrier below
      const float* kb = kb0 + (nt + 1) * 2048;
      const float* vb = vb0 + (nt + 1) * 2048;
#pragma unroll
      for (int hh = 0; hh < 2; ++hh) {
        int f = t + hh * 256;
        kx[hh] = *(const f32x4*)(kb + (f >> 4) * 64 + (f & 15) * 4);
        vx[hh] = *(const f32x4*)(vb + (f >> 4) * 64 + (f & 15) * 4);
      }
    }
    BARRIER_LGKM();  // A: staged tile visible

    short8 afr[2][2];
#pragma unroll
    for (int nh1 = 0; nh1 < 2; ++nh1)
#pragma unroll
      for (int kk = 0; kk < 2; ++kk)
        afr[nh1][kk] = *(const short8*)&sX[nh1 * 16 + c][kk * 32 + g * 8];

    f32x4 acc1[2][4];
#pragma unroll
    for (int i = 0; i < 2; ++i)
#pragma unroll
      for (int j = 0; j < 4; ++j) acc1[i][j] = (f32x4){0.f, 0.f, 0.f, 0.f};
#pragma unroll
    for (int kk = 0; kk < 2; ++kk)
#pragma unroll
      for (int nh1 = 0; nh1 < 2; ++nh1)
#pragma unroll
        for (int mt = 0; mt < 4; ++mt)
          acc1[nh1][mt] = __builtin_amdgcn_mfma_f32_16x16x32_bf16(
              afr[nh1][kk], pfrag[mt][kk], acc1[nh1][mt], 0, 0, 0);

#pragma unroll
    for (int nh1 = 0; nh1 < 2; ++nh1)
#pragma unroll
      for (int mt = 0; mt < 4; ++mt) {
        int m = wid * 64 + mt * 16 + c;
        unsigned short wp[4];
#pragma unroll
        for (int r = 0; r < 4; ++r) {
          float dd = acc1[nh1][mt][r];
          gm = fmaxf(gm, dd);
          int n = nh1 * 16 + g * 4 + r;
          float w = EXP2F(dd - sDiag[n]);
          unsigned short wb = f2bf(w);
          kexpreg[mt] += bf2f(wb);
          wp[r] = wb;
        }
        us4 w4 = {wp[0], wp[1], wp[2], wp[3]};
        *(us4*)&sW[m][nh1 * 16 + g * 4] = w4;
      }

    // GEMM2 reads wave-private sW + post-barrier sVt: no barrier needed.
    short8 awt[4], bvv[4];
#pragma unroll
    for (int mt2 = 0; mt2 < 4; ++mt2)
      awt[mt2] = *(const short8*)&sW[wid * 64 + mt2 * 16 + c][g * 8];
#pragma unroll
    for (int et = 0; et < 4; ++et)
      bvv[et] = *(const short8*)&sVt[et * 16 + c][g * 8];
#pragma unroll
    for (int mt2 = 0; mt2 < 4; ++mt2)
#pragma unroll
      for (int et = 0; et < 4; ++et)
        ctx[mt2][et] = __builtin_amdgcn_mfma_f32_16x16x32_bf16(
            awt[mt2], bvv[et], ctx[mt2][et], 0, 0, 0);
  }

#pragma unroll
  for (int mt2 = 0; mt2 < 4; ++mt2)
#pragma unroll
    for (int et = 0; et < 4; ++et) {
      int m0 = wid * 64 + mt2 * 16 + g * 4;
      int e = et * 16 + c;
      size_t base = (((size_t)chunk * BH_ + bh) * 64 + e) * 256 + m0;
      *(f32x4*)(ctxp + base) = ctx[mt2][et];
    }
#pragma unroll
  for (int mt = 0; mt < 4; ++mt) {
    float s = kexpreg[mt];
    s += __shfl_xor(s, 16);
    s += __shfl_xor(s, 32);
    if (lane < 16)
      kexpp[((size_t)chunk * BH_ + bh) * 256 + wid * 64 + mt * 16 + lane] = s;
  }
  if (t < 64) sVsum[t] = 0.f;
  __syncthreads();
  atomicAdd(&sVsum[(t & 15) * 4 + 0], vsum0);
  atomicAdd(&sVsum[(t & 15) * 4 + 1], vsum1);
  atomicAdd(&sVsum[(t & 15) * 4 + 2], vsum2);
  atomicAdd(&sVsum[(t & 15) * 4 + 3], vsum3);
  __syncthreads();
  if (t < 64) vsump[((size_t)chunk * BH_ + bh) * 64 + t] = sVsum[t];

  gm = fmaxf(gm, __shfl_xor(gm, 1));
  gm = fmaxf(gm, __shfl_xor(gm, 2));
  gm = fmaxf(gm, __shfl_xor(gm, 4));
  gm = fmaxf(gm, __shfl_xor(gm, 8));
  gm = fmaxf(gm, __shfl_xor(gm, 16));
  gm = fmaxf(gm, __shfl_xor(gm, 32));
  if (lane == 0) sGm[wid] = gm;
  __syncthreads();
  if (t == 0) {
    float mm = fmaxf(fmaxf(sGm[0], sGm[1]), fmaxf(sGm[2], sGm[3]));
    atomicMax((int*)gmaxb, __float_as_int(mm));  // gmax2 > 0 in practice
  }
}

// ---------------------------------------------------------------------------
// Rescale: CTX = 2^-g*sum(ctx)+eps*vsum -> bf16 [bh][e][m];
//          KC  = 2^-g*sum(kexp)+eps*N   -> bf16 hi/lo split (f32 accuracy).
// ---------------------------------------------------------------------------
__global__ void perf_rescale(const float* __restrict__ ctxp,
                             const float* __restrict__ kexpp,
                             const float* __restrict__ vsump,
                             unsigned short* __restrict__ ctxt,
                             unsigned short* __restrict__ kchi,
                             unsigned short* __restrict__ kclo,
                             const unsigned int* __restrict__ gmaxb, int nchunk) {
  const int bh = blockIdx.x >> 3;
  const int es = blockIdx.x & 7;
  const int t = threadIdx.x;  // m
  const float gmax = __uint_as_float(*gmaxb);
  const float s = EXP2F(-gmax);
  if (es == 0) {
    float acc = 0.f;
    for (int cc = 0; cc < nchunk; ++cc)
      acc += kexpp[((size_t)cc * BH_ + bh) * 256 + t];
    float kcv = s * acc + EPSF * (float)N_;
    unsigned short hi = f2bf(kcv);
    kchi[bh * 256 + t] = hi;
    kclo[bh * 256 + t] = f2bf(kcv - bf2f(hi));
  }
  for (int e = es * 8; e < es * 8 + 8; ++e) {
    float vs = 0.f;
    for (int cc = 0; cc < nchunk; ++cc)
      vs += vsump[((size_t)cc * BH_ + bh) * 64 + e];
    float a2 = 0.f;
    for (int cc = 0; cc < nchunk; ++cc)
      a2 += ctxp[(((size_t)cc * BH_ + bh) * 64 + e) * 256 + t];
    ctxt[((size_t)bh * 64 + e) * 256 + t] = f2bf(s * a2 + EPSF * vs);
  }
}

// ---------------------------------------------------------------------------
// Q pass v3 — one wave per 16 rows, fully independent: no barriers, no sX.
// X loaded per-lane direct from global; diag via in-lane sum + shfl across g;
// rowmax in-lane + shfl; qt transpose via the wave's own 8.25KB sQt (same-
// wave DS ordering, no barrier — same idiom as kpass sW). P/CTX stream from
// L1/L2 (P universal 32KB; CTX 32KB per bh, consecutive blocks share bh).
// r5 post-mortem: v2's 4-wave/52KB-LDS structure was latency-bound at 23%
// occupancy with MFMAs chained on L2 loads; this maximizes resident waves.
// ---------------------------------------------------------------------------
__global__ __launch_bounds__(64, 3)
void perf_qpass(const float* __restrict__ qp,
                const unsigned short* __restrict__ projb,
                const unsigned short* __restrict__ ctxt,
                const unsigned short* __restrict__ kchi,
                const unsigned short* __restrict__ kclo,
                float* __restrict__ outp) {
  const int bh = blockIdx.x >> 8;
  const int tile = blockIdx.x & 255;  // 16 rows per wave
  const int lane = threadIdx.x;
  const int g = lane >> 4;
  const int c = lane & 15;

  __shared__ __align__(16) unsigned short sQt[16][264];

  const unsigned short* ctxb = ctxt + (size_t)bh * 64 * 256;
  const unsigned short* khib = kchi + bh * 256;
  const unsigned short* klob = kclo + bh * 256;
  const unsigned short* pb = projb + c * 64 + g * 8;  // + mt*1024 (+32 kk=1)

  const float* qrow = qp + ((size_t)bh * N_ + tile * 16 + c) * 64;
  float* ob0 = outp + ((size_t)bh * N_ + tile * 16) * 64;

  // ---- X fragments direct from global: lane (g,c) = row c, k=g*8..+7 ----
  f32x4 x0 = *(const f32x4*)(qrow + g * 8);
  f32x4 x1 = *(const f32x4*)(qrow + g * 8 + 4);
  f32x4 x2 = *(const f32x4*)(qrow + 32 + g * 8);
  f32x4 x3 = *(const f32x4*)(qrow + 32 + g * 8 + 4);

  float ss = x0[0]*x0[0] + x0[1]*x0[1] + x0[2]*x0[2] + x0[3]*x0[3]
           + x1[0]*x1[0] + x1[1]*x1[1] + x1[2]*x1[2] + x1[3]*x1[3]
           + x2[0]*x2[0] + x2[1]*x2[1] + x2[2]*x2[2] + x2[3]*x2[3]
           + x3[0]*x3[0] + x3[1]*x3[1] + x3[2]*x3[2] + x3[3]*x3[3];
  ss += __shfl_xor(ss, 16);
  ss += __shfl_xor(ss, 32);
  const float diag = DIAGL * ss;

  short8 xb0, xb1;
#pragma unroll
  for (int j = 0; j < 4; ++j) {
    xb0[j] = (short)f2bf(x0[j]);
    xb0[j + 4] = (short)f2bf(x1[j]);
    xb1[j] = (short)f2bf(x2[j]);
    xb1[j + 4] = (short)f2bf(x3[j]);
  }

  // ---- GEMM1: dd^T[256m x 16n]; lane (g,c): m=mt*16+g*4+r, n=c ----
  f32x4 acc1[16];
#pragma unroll
  for (int mt = 0; mt < 16; ++mt) acc1[mt] = (f32x4){0.f, 0.f, 0.f, 0.f};
#pragma unroll
  for (int mt = 0; mt < 16; ++mt) {
    short8 p0 = *(const short8*)(pb + mt * 1024);
    short8 p1 = *(const short8*)(pb + mt * 1024 + 32);
    acc1[mt] = __builtin_amdgcn_mfma_f32_16x16x32_bf16(p0, xb0, acc1[mt], 0, 0, 0);
    acc1[mt] = __builtin_amdgcn_mfma_f32_16x16x32_bf16(p1, xb1, acc1[mt], 0, 0, 0);
  }

  // ---- rowmax over all 256 m: in-lane + 2 shfl across g ----
  float mx = acc1[0][0];
#pragma unroll
  for (int mt = 0; mt < 16; ++mt)
#pragma unroll
    for (int r = 0; r < 4; ++r) mx = fmaxf(mx, acc1[mt][r]);
  mx = fmaxf(mx, __shfl_xor(mx, 16));
  mx = fmaxf(mx, __shfl_xor(mx, 32));
  const float base = diag + mx;

  // ---- qt = exp2(dd-base)+eps -> bf16 pairs -> own sQt (no barrier) ----
#pragma unroll
  for (int mt = 0; mt < 16; ++mt) {
    float q0 = EXP2F(acc1[mt][0] - base) + EPSF;
    float q1 = EXP2F(acc1[mt][1] - base) + EPSF;
    float q2 = EXP2F(acc1[mt][2] - base) + EPSF;
    float q3 = EXP2F(acc1[mt][3] - base) + EPSF;
    uint2 d;
    d.x = pk2bf(q0, q1);
    d.y = pk2bf(q2, q3);
    *(uint2*)&sQt[c][mt * 16 + g * 4] = d;
  }

  // ---- GEMM2: out[16n x 64e] = qt · CTX^T ; acc2[4] = den (kc hi/lo) ----
  f32x4 acc2[5];
#pragma unroll
  for (int et = 0; et < 5; ++et) acc2[et] = (f32x4){0.f, 0.f, 0.f, 0.f};
  const short8 bz = {0, 0, 0, 0, 0, 0, 0, 0};
#pragma unroll
  for (int kc2 = 0; kc2 < 8; ++kc2) {
    short8 a = *(const short8*)&sQt[c][kc2 * 32 + g * 8];
#pragma unroll
    for (int et = 0; et < 4; ++et) {
      short8 b = *(const short8*)&ctxb[(et * 16 + c) * 256 + kc2 * 32 + g * 8];
      acc2[et] = __builtin_amdgcn_mfma_f32_16x16x32_bf16(a, b, acc2[et], 0, 0, 0);
    }
    short8 hi8 = *(const short8*)&khib[kc2 * 32 + g * 8];
    short8 lo8 = *(const short8*)&klob[kc2 * 32 + g * 8];
    short8 bden = (c == 0) ? hi8 : ((c == 1) ? lo8 : bz);
    acc2[4] = __builtin_amdgcn_mfma_f32_16x16x32_bf16(a, bden, acc2[4], 0, 0, 0);
  }

  // ---- den broadcast + divide + store: lane holds n=g*4+r, e=et*16+c ----
#pragma unroll
  for (int r = 0; r < 4; ++r) {
    float den = __shfl(acc2[4][r], g * 16) + __shfl(acc2[4][r], g * 16 + 1);
    float rinv = 1.0f / den;
    int n = g * 4 + r;
#pragma unroll
    for (int et = 0; et < 4; ++et)
      ob0[(size_t)n * 64 + et * 16 + c] = acc2[et][r] * rinv;
  }
}

extern "C" void kernel_launch(void* const* d_in, const int* in_sizes, int n_in,
                              void* d_out, int out_size, void* d_ws, size_t ws_size,
                              hipStream_t stream) {
  (void)in_sizes; (void)n_in; (void)out_size;
  const float* qp = (const float*)d_in[0];
  const float* kp = (const float*)d_in[1];
  const float* vp = (const float*)d_in[2];
  const float* proj = (const float*)d_in[3];
  float* outp = (float*)d_out;

  int nchunk = 8;
  while (nchunk > 1) {
    size_t fl = 64 + (size_t)nchunk * (2097152 + 32768 + 8192);
    size_t needed = fl * 4 + (size_t)(2097152 + 32768 + 32768 + 16384) * 2;
    if (needed <= ws_size) break;
    nchunk >>= 1;
  }

  float* wsf = (float*)d_ws;
  unsigned int* gmaxb = (unsigned int*)d_ws;
  float* ctxp = wsf + 64;
  float* kexpp = ctxp + (size_t)nchunk * 128 * 64 * 256;
  float* vsump = kexpp + (size_t)nchunk * 128 * 256;
  unsigned short* ctxt = (unsigned short*)(vsump + (size_t)nchunk * 128 * 64);
  unsigned short* kchi = ctxt + (size_t)128 * 64 * 256;
  unsigned short* kclo = kchi + 128 * 256;
  unsigned short* projb = kclo + 128 * 256;

  hipMemsetAsync(d_ws, 0, 16, stream);
  hipLaunchKernelGGL(perf_prep, dim3(64), dim3(256), 0, stream, proj, projb);
  hipLaunchKernelGGL(perf_kpass, dim3(128 * nchunk), dim3(256), 0, stream,
                     kp, vp, proj, ctxp, kexpp, vsump, gmaxb, nchunk);
  hipLaunchKernelGGL(perf_rescale, dim3(128 * 8), dim3(256), 0, stream,
                     ctxp, kexpp, vsump, ctxt, kchi, kclo, gmaxb, nchunk);
  hipLaunchKernelGGL(perf_qpass, dim3(128 * 256), dim3(64), 0, stream,
                     qp, projb, ctxt, kchi, kclo, outp);
}

// Round 7
// 196.046 us; speedup vs baseline: 2.7158x; 2.0922x over previous
//
#include <hip/hip_runtime.h>
#include <hip/hip_bf16.h>

typedef __attribute__((ext_vector_type(4))) float f32x4;
typedef __attribute__((ext_vector_type(8))) short short8;
typedef __attribute__((ext_vector_type(4))) unsigned short us4;
typedef __attribute__((ext_vector_type(4))) unsigned int u32x4;

#define BH_ 128
#define N_ 4096
#define LOG2E 1.4426950408889634f
#define NORML (0.35355339059327373f * LOG2E)  // d^-0.25 * log2(e) folded into P
#define DIAGL (0.0625f * LOG2E)               // 0.5*d^-0.5 * log2(e)
#define EPSF 1e-4f

#if __has_builtin(__builtin_amdgcn_exp2f)
#define EXP2F(x) __builtin_amdgcn_exp2f(x)
#else
#define EXP2F(x) exp2f(x)
#endif

// LDS-only barrier: orders ds_write/ds_read across waves WITHOUT draining
// vmcnt — in-flight global prefetch loads survive the barrier (T4).
#define BARRIER_LGKM() asm volatile("s_waitcnt lgkmcnt(0)\ns_barrier" ::: "memory")

static __device__ __forceinline__ unsigned short f2bf(float f) {
  return __bfloat16_as_ushort(__float2bfloat16(f));  // RNE, HW cvt
}
static __device__ __forceinline__ float bf2f(unsigned short s) {
  return __uint_as_float(((unsigned int)s) << 16);
}
static __device__ __forceinline__ us4 cvt4(f32x4 x) {
  us4 r;
  r[0] = f2bf(x[0]); r[1] = f2bf(x[1]); r[2] = f2bf(x[2]); r[3] = f2bf(x[3]);
  return r;
}
static __device__ __forceinline__ unsigned int pk2bf(float lo, float hi) {
  unsigned int r;
  asm("v_cvt_pk_bf16_f32 %0, %1, %2" : "=v"(r) : "v"(lo), "v"(hi));
  return r;
}

// m-permutation used for the GEMM2 contraction (bijective bit shuffle):
// pos = [b7 b6 b5 | b3 b2 | b4 | b1 b0].  With CTX/kc columns stored at
// pos(m), each qpass lane's GEMM1 outputs ARE its GEMM2 A-fragment.
static __device__ __forceinline__ int posm(int m) {
  return (m & 0xE0) | ((m & 0xC) << 1) | ((m & 0x10) >> 2) | (m & 3);
}

// ---------------------------------------------------------------------------
// prep: projection -> bf16 with NORML folded (consumed by qpass GEMM1).
// ---------------------------------------------------------------------------
__global__ void perf_prep(const float* __restrict__ proj,
                          unsigned short* __restrict__ projb) {
  int i = blockIdx.x * 256 + threadIdx.x;  // 16384 total
  projb[i] = f2bf(proj[i] * NORML);
}

// ---------------------------------------------------------------------------
// K pass (log2 domain) — unchanged from round 5 (one-variable discipline).
// RULE (r2/r4): __launch_bounds__(256,2); tighter bounds spill.
// ---------------------------------------------------------------------------
__global__ __launch_bounds__(256, 2)
void perf_kpass(const float* __restrict__ kp, const float* __restrict__ vp,
                const float* __restrict__ proj, float* __restrict__ ctxp,
                float* __restrict__ kexpp, float* __restrict__ vsump,
                unsigned int* __restrict__ gmaxb, int nchunk) {
  const int bh = blockIdx.x & (BH_ - 1);
  const int chunk = blockIdx.x >> 7;
  const int chunkrows = N_ / nchunk;
  const int tiles = chunkrows >> 5;
  const int t = threadIdx.x;
  const int wid = t >> 6;
  const int lane = t & 63;
  const int g = lane >> 4;
  const int c = lane & 15;

  __shared__ __align__(16) unsigned short sX[32][72];
  __shared__ __align__(16) unsigned short sVt[64][40];
  __shared__ __align__(16) unsigned short sW[256][40];
  __shared__ float sDiag[32];
  __shared__ float sVsum[64];
  __shared__ float sGm[4];

  short8 pfrag[4][2];
#pragma unroll
  for (int mt = 0; mt < 4; ++mt)
#pragma unroll
    for (int kk = 0; kk < 2; ++kk) {
      const float* src = proj + (wid * 64 + mt * 16 + c) * 64 + kk * 32 + g * 8;
      short8 v;
#pragma unroll
      for (int j = 0; j < 8; ++j) v[j] = (short)f2bf(src[j] * NORML);
      pfrag[mt][kk] = v;
    }

  f32x4 ctx[4][4];
#pragma unroll
  for (int i = 0; i < 4; ++i)
#pragma unroll
    for (int j = 0; j < 4; ++j) ctx[i][j] = (f32x4){0.f, 0.f, 0.f, 0.f};

  float kexpreg[4] = {0.f, 0.f, 0.f, 0.f};
  float vsum0 = 0.f, vsum1 = 0.f, vsum2 = 0.f, vsum3 = 0.f;
  float gm = -1e30f;

  const float* kb0 = kp + ((size_t)bh * N_ + (size_t)chunk * chunkrows) * 64;
  const float* vb0 = vp + ((size_t)bh * N_ + (size_t)chunk * chunkrows) * 64;

  f32x4 kx[2], vx[2];
#pragma unroll
  for (int hh = 0; hh < 2; ++hh) {
    int f = t + hh * 256;
    kx[hh] = *(const f32x4*)(kb0 + (f >> 4) * 64 + (f & 15) * 4);
    vx[hh] = *(const f32x4*)(vb0 + (f >> 4) * 64 + (f & 15) * 4);
  }

  for (int nt = 0; nt < tiles; ++nt) {
    BARRIER_LGKM();  // S: prev tile's ds_reads done before overwrite
#pragma unroll
    for (int hh = 0; hh < 2; ++hh) {
      int f = t + hh * 256;
      int row = f >> 4;
      int c4 = f & 15;
      f32x4 x = kx[hh];
      float ss = x[0] * x[0] + x[1] * x[1] + x[2] * x[2] + x[3] * x[3];
      ss += __shfl_xor(ss, 1);
      ss += __shfl_xor(ss, 2);
      ss += __shfl_xor(ss, 4);
      ss += __shfl_xor(ss, 8);
      if (c4 == 0) sDiag[row] = DIAGL * ss;
      *(us4*)&sX[row][c4 * 4] = cvt4(x);
      f32x4 vv = vx[hh];
      vsum0 += vv[0]; vsum1 += vv[1]; vsum2 += vv[2]; vsum3 += vv[3];
#pragma unroll
      for (int jj = 0; jj < 4; ++jj) {
        int j = (jj + t) & 3;  // rotate to spread banks
        float val = (j == 0) ? vv[0] : (j == 1) ? vv[1] : (j == 2) ? vv[2] : vv[3];
        sVt[c4 * 4 + j][row] = f2bf(val);
      }
    }
    if (nt + 1 < tiles) {  // prefetch survives the lgkm-only barrier below
      const float* kb = kb0 + (nt + 1) * 2048;
      const float* vb = vb0 + (nt + 1) * 2048;
#pragma unroll
      for (int hh = 0; hh < 2; ++hh) {
        int f = t + hh * 256;
        kx[hh] = *(const f32x4*)(kb + (f >> 4) * 64 + (f & 15) * 4);
        vx[hh] = *(const f32x4*)(vb + (f >> 4) * 64 + (f & 15) * 4);
      }
    }
    BARRIER_LGKM();  // A: staged tile visible

    short8 afr[2][2];
#pragma unroll
    for (int nh1 = 0; nh1 < 2; ++nh1)
#pragma unroll
      for (int kk = 0; kk < 2; ++kk)
        afr[nh1][kk] = *(const short8*)&sX[nh1 * 16 + c][kk * 32 + g * 8];

    f32x4 acc1[2][4];
#pragma unroll
    for (int i = 0; i < 2; ++i)
#pragma unroll
      for (int j = 0; j < 4; ++j) acc1[i][j] = (f32x4){0.f, 0.f, 0.f, 0.f};
#pragma unroll
    for (int kk = 0; kk < 2; ++kk)
#pragma unroll
      for (int nh1 = 0; nh1 < 2; ++nh1)
#pragma unroll
        for (int mt = 0; mt < 4; ++mt)
          acc1[nh1][mt] = __builtin_amdgcn_mfma_f32_16x16x32_bf16(
              afr[nh1][kk], pfrag[mt][kk], acc1[nh1][mt], 0, 0, 0);

#pragma unroll
    for (int nh1 = 0; nh1 < 2; ++nh1)
#pragma unroll
      for (int mt = 0; mt < 4; ++mt) {
        int m = wid * 64 + mt * 16 + c;
        unsigned short wp[4];
#pragma unroll
        for (int r = 0; r < 4; ++r) {
          float dd = acc1[nh1][mt][r];
          gm = fmaxf(gm, dd);
          int n = nh1 * 16 + g * 4 + r;
          float w = EXP2F(dd - sDiag[n]);
          unsigned short wb = f2bf(w);
          kexpreg[mt] += bf2f(wb);
          wp[r] = wb;
        }
        us4 w4 = {wp[0], wp[1], wp[2], wp[3]};
        *(us4*)&sW[m][nh1 * 16 + g * 4] = w4;
      }

    // GEMM2 reads wave-private sW + post-barrier sVt: no barrier needed.
    short8 awt[4], bvv[4];
#pragma unroll
    for (int mt2 = 0; mt2 < 4; ++mt2)
      awt[mt2] = *(const short8*)&sW[wid * 64 + mt2 * 16 + c][g * 8];
#pragma unroll
    for (int et = 0; et < 4; ++et)
      bvv[et] = *(const short8*)&sVt[et * 16 + c][g * 8];
#pragma unroll
    for (int mt2 = 0; mt2 < 4; ++mt2)
#pragma unroll
      for (int et = 0; et < 4; ++et)
        ctx[mt2][et] = __builtin_amdgcn_mfma_f32_16x16x32_bf16(
            awt[mt2], bvv[et], ctx[mt2][et], 0, 0, 0);
  }

#pragma unroll
  for (int mt2 = 0; mt2 < 4; ++mt2)
#pragma unroll
    for (int et = 0; et < 4; ++et) {
      int m0 = wid * 64 + mt2 * 16 + g * 4;
      int e = et * 16 + c;
      size_t base = (((size_t)chunk * BH_ + bh) * 64 + e) * 256 + m0;
      *(f32x4*)(ctxp + base) = ctx[mt2][et];
    }
#pragma unroll
  for (int mt = 0; mt < 4; ++mt) {
    float s = kexpreg[mt];
    s += __shfl_xor(s, 16);
    s += __shfl_xor(s, 32);
    if (lane < 16)
      kexpp[((size_t)chunk * BH_ + bh) * 256 + wid * 64 + mt * 16 + lane] = s;
  }
  if (t < 64) sVsum[t] = 0.f;
  __syncthreads();
  atomicAdd(&sVsum[(t & 15) * 4 + 0], vsum0);
  atomicAdd(&sVsum[(t & 15) * 4 + 1], vsum1);
  atomicAdd(&sVsum[(t & 15) * 4 + 2], vsum2);
  atomicAdd(&sVsum[(t & 15) * 4 + 3], vsum3);
  __syncthreads();
  if (t < 64) vsump[((size_t)chunk * BH_ + bh) * 64 + t] = sVsum[t];

  gm = fmaxf(gm, __shfl_xor(gm, 1));
  gm = fmaxf(gm, __shfl_xor(gm, 2));
  gm = fmaxf(gm, __shfl_xor(gm, 4));
  gm = fmaxf(gm, __shfl_xor(gm, 8));
  gm = fmaxf(gm, __shfl_xor(gm, 16));
  gm = fmaxf(gm, __shfl_xor(gm, 32));
  if (lane == 0) sGm[wid] = gm;
  __syncthreads();
  if (t == 0) {
    float mm = fmaxf(fmaxf(sGm[0], sGm[1]), fmaxf(sGm[2], sGm[3]));
    atomicMax((int*)gmaxb, __float_as_int(mm));  // gmax2 > 0 in practice
  }
}

// ---------------------------------------------------------------------------
// Rescale: CTX -> bf16 [bh][e][pos(m)]; KC -> bf16 hi/lo at pos(m).
// Columns scattered through posm() so qpass GEMM2 needs zero shuffles.
// ---------------------------------------------------------------------------
__global__ void perf_rescale(const float* __restrict__ ctxp,
                             const float* __restrict__ kexpp,
                             const float* __restrict__ vsump,
                             unsigned short* __restrict__ ctxt,
                             unsigned short* __restrict__ kchi,
                             unsigned short* __restrict__ kclo,
                             const unsigned int* __restrict__ gmaxb, int nchunk) {
  const int bh = blockIdx.x >> 3;
  const int es = blockIdx.x & 7;
  const int t = threadIdx.x;  // m (source order)
  const int pos = posm(t);
  const float gmax = __uint_as_float(*gmaxb);
  const float s = EXP2F(-gmax);
  if (es == 0) {
    float acc = 0.f;
    for (int cc = 0; cc < nchunk; ++cc)
      acc += kexpp[((size_t)cc * BH_ + bh) * 256 + t];
    float kcv = s * acc + EPSF * (float)N_;
    unsigned short hi = f2bf(kcv);
    kchi[bh * 256 + pos] = hi;
    kclo[bh * 256 + pos] = f2bf(kcv - bf2f(hi));
  }
  for (int e = es * 8; e < es * 8 + 8; ++e) {
    float vs = 0.f;
    for (int cc = 0; cc < nchunk; ++cc)
      vs += vsump[((size_t)cc * BH_ + bh) * 64 + e];
    float a2 = 0.f;
    for (int cc = 0; cc < nchunk; ++cc)
      a2 += ctxp[(((size_t)cc * BH_ + bh) * 64 + e) * 256 + t];
    ctxt[((size_t)bh * 64 + e) * 256 + pos] = f2bf(s * a2 + EPSF * vs);
  }
}

// ---------------------------------------------------------------------------
// Q pass v4 — block stages P/CTX/kc into swizzled LDS once (4 waves, 512
// rows/block); waves then independent, zero per-tile barriers. Swapped GEMM1
// gives wave-local softmax; the posm() column permutation makes each lane's
// GEMM1 outputs its GEMM2 A-fragment directly (no LDS round-trip, no shfl).
// XOR slot swizzle (slot ^= row&7) -> 2-way conflicts only (free, m136).
// r6 post-mortem: v3 was L2-latency-bound (64KB operand set > L1, serialized
// misses); LDS staging + chunked 8-deep ds_read pipeline removes that path.
// ---------------------------------------------------------------------------
__global__ __launch_bounds__(256, 2)
void perf_qpass(const float* __restrict__ qp,
                const unsigned short* __restrict__ projb,
                const unsigned short* __restrict__ ctxt,
                const unsigned short* __restrict__ kchi,
                const unsigned short* __restrict__ kclo,
                float* __restrict__ outp) {
  const int bh = blockIdx.x >> 3;
  const int chunk = blockIdx.x & 7;  // 512 rows per block
  const int t = threadIdx.x;
  const int wid = t >> 6;
  const int lane = t & 63;
  const int g = lane >> 4;
  const int c = lane & 15;

  __shared__ __align__(16) unsigned short sP[256 * 64];   // 32KB, swizzled
  __shared__ __align__(16) unsigned short sC[64 * 256];   // 32KB, swizzled
  __shared__ __align__(16) unsigned short sC2[16 * 256];  // 8KB: kc hi/lo tile

  const unsigned short* csrc = ctxt + (size_t)bh * 64 * 256;
  const unsigned short* khib = kchi + bh * 256;
  const unsigned short* klob = kclo + bh * 256;

  const float* qbase = qp + ((size_t)bh * N_ + chunk * 512 + wid * 128) * 64;
  float* obase = outp + ((size_t)bh * N_ + chunk * 512 + wid * 128) * 64;

  // ---- prefetch tile 0 X (lane (g,c): row c, k = g*8.. & 32+g*8..) ----
  const float* q0 = qbase + (size_t)c * 64 + g * 8;
  f32x4 xp0 = *(const f32x4*)(q0);
  f32x4 xp1 = *(const f32x4*)(q0 + 4);
  f32x4 xp2 = *(const f32x4*)(q0 + 32);
  f32x4 xp3 = *(const f32x4*)(q0 + 36);

  // ---- cooperative staging, 16B slots XOR-swizzled by (row&7) ----
#pragma unroll
  for (int rep = 0; rep < 8; ++rep) {
    int e = rep * 2048 + t * 8;
    {
      int row = e >> 6, slot = (e & 63) >> 3;  // sP row=128B=8 slots
      short8 v = *(const short8*)(projb + e);
      *(short8*)((char*)sP + row * 128 + ((slot ^ (row & 7)) << 4)) = v;
    }
    {
      int row = e >> 8, slot = (e & 255) >> 3;  // sC row=512B=32 slots
      short8 v = *(const short8*)(csrc + e);
      *(short8*)((char*)sC + row * 512 + ((slot ^ (row & 7)) << 4)) = v;
    }
  }
#pragma unroll
  for (int rep = 0; rep < 2; ++rep) {
    int e = rep * 2048 + t * 8;
    int row = e >> 8, col = e & 255, slot = col >> 3;
    short8 v = {0, 0, 0, 0, 0, 0, 0, 0};
    if (row == 0) v = *(const short8*)(khib + col);
    if (row == 1) v = *(const short8*)(klob + col);
    *(short8*)((char*)sC2 + row * 512 + ((slot ^ (row & 7)) << 4)) = v;
  }
  __syncthreads();  // once per block (512 rows) — staging visible

  // per-lane swizzled byte offsets: slot(kk,g) ^ (c&7) = (kk^b6)*4 + (g^(c&3))
  const int gsw = (g ^ (c & 3)) << 4;
  const int b6 = (c >> 2) & 1;
  const int pb0 = c * 128 + (b6 << 6) + gsw;        // P: logical kk=0
  const int pb1 = c * 128 + ((1 ^ b6) << 6) + gsw;  // P: logical kk=1
  const char* spc = (const char*)sP;
  const char* scc = (const char*)sC + c * 512;
  const char* sc2c = (const char*)sC2 + c * 512;

#pragma unroll 1
  for (int tt = 0; tt < 8; ++tt) {
    f32x4 x0 = xp0, x1 = xp1, x2 = xp2, x3 = xp3;
    if (tt + 1 < 8) {  // prefetch next tile; no barriers -> stays in flight
      const float* qn = qbase + ((size_t)((tt + 1) * 16 + c)) * 64 + g * 8;
      xp0 = *(const f32x4*)(qn);
      xp1 = *(const f32x4*)(qn + 4);
      xp2 = *(const f32x4*)(qn + 32);
      xp3 = *(const f32x4*)(qn + 36);
    }
    float ss = x0[0]*x0[0] + x0[1]*x0[1] + x0[2]*x0[2] + x0[3]*x0[3]
             + x1[0]*x1[0] + x1[1]*x1[1] + x1[2]*x1[2] + x1[3]*x1[3]
             + x2[0]*x2[0] + x2[1]*x2[1] + x2[2]*x2[2] + x2[3]*x2[3]
             + x3[0]*x3[0] + x3[1]*x3[1] + x3[2]*x3[2] + x3[3]*x3[3];
    ss += __shfl_xor(ss, 16);
    ss += __shfl_xor(ss, 32);
    const float diag = DIAGL * ss;

    short8 xb0, xb1;
#pragma unroll
    for (int j = 0; j < 4; ++j) {
      xb0[j] = (short)f2bf(x0[j]);
      xb0[j + 4] = (short)f2bf(x1[j]);
      xb1[j] = (short)f2bf(x2[j]);
      xb1[j + 4] = (short)f2bf(x3[j]);
    }

    // ---- GEMM1: dd^T = P · X^T, chunked 2-buffer LDS pipeline ----
    f32x4 acc1[16];
#pragma unroll
    for (int mt = 0; mt < 16; ++mt) acc1[mt] = (f32x4){0.f, 0.f, 0.f, 0.f};
    short8 Ak0[4], Ak1[4], Bk0[4], Bk1[4];
#pragma unroll
    for (int i = 0; i < 4; ++i) {
      Ak0[i] = *(const short8*)(spc + i * 2048 + pb0);
      Ak1[i] = *(const short8*)(spc + i * 2048 + pb1);
    }
#pragma unroll
    for (int i = 0; i < 4; ++i) {
      Bk0[i] = *(const short8*)(spc + (4 + i) * 2048 + pb0);
      Bk1[i] = *(const short8*)(spc + (4 + i) * 2048 + pb1);
    }
#pragma unroll
    for (int i = 0; i < 4; ++i) {
      acc1[i] = __builtin_amdgcn_mfma_f32_16x16x32_bf16(Ak0[i], xb0, acc1[i], 0, 0, 0);
      acc1[i] = __builtin_amdgcn_mfma_f32_16x16x32_bf16(Ak1[i], xb1, acc1[i], 0, 0, 0);
    }
#pragma unroll
    for (int i = 0; i < 4; ++i) {
      Ak0[i] = *(const short8*)(spc + (8 + i) * 2048 + pb0);
      Ak1[i] = *(const short8*)(spc + (8 + i) * 2048 + pb1);
    }
#pragma unroll
    for (int i = 0; i < 4; ++i) {
      acc1[4 + i] = __builtin_amdgcn_mfma_f32_16x16x32_bf16(Bk0[i], xb0, acc1[4 + i], 0, 0, 0);
      acc1[4 + i] = __builtin_amdgcn_mfma_f32_16x16x32_bf16(Bk1[i], xb1, acc1[4 + i], 0, 0, 0);
    }
#pragma unroll
    for (int i = 0; i < 4; ++i) {
      Bk0[i] = *(const short8*)(spc + (12 + i) * 2048 + pb0);
      Bk1[i] = *(const short8*)(spc + (12 + i) * 2048 + pb1);
    }
#pragma unroll
    for (int i = 0; i < 4; ++i) {
      acc1[8 + i] = __builtin_amdgcn_mfma_f32_16x16x32_bf16(Ak0[i], xb0, acc1[8 + i], 0, 0, 0);
      acc1[8 + i] = __builtin_amdgcn_mfma_f32_16x16x32_bf16(Ak1[i], xb1, acc1[8 + i], 0, 0, 0);
    }
#pragma unroll
    for (int i = 0; i < 4; ++i) {
      acc1[12 + i] = __builtin_amdgcn_mfma_f32_16x16x32_bf16(Bk0[i], xb0, acc1[12 + i], 0, 0, 0);
      acc1[12 + i] = __builtin_amdgcn_mfma_f32_16x16x32_bf16(Bk1[i], xb1, acc1[12 + i], 0, 0, 0);
    }
    // lane (g,c): dd[m = mt*16 + g*4 + r][n = c]

    // ---- rowmax (in-lane 64 + 2 shfl across g) -> base ----
    float mx = acc1[0][0];
#pragma unroll
    for (int mt = 0; mt < 16; ++mt)
#pragma unroll
      for (int r = 0; r < 4; ++r) mx = fmaxf(mx, acc1[mt][r]);
    mx = fmaxf(mx, __shfl_xor(mx, 16));
    mx = fmaxf(mx, __shfl_xor(mx, 32));
    const float base = diag + mx;

    // ---- qt = exp2(dd - base) + eps, packed; this IS the GEMM2 A-frag ----
    uint2 qtp[16];
#pragma unroll
    for (int mt = 0; mt < 16; ++mt) {
      float qa = EXP2F(acc1[mt][0] - base) + EPSF;
      float qb = EXP2F(acc1[mt][1] - base) + EPSF;
      float qc = EXP2F(acc1[mt][2] - base) + EPSF;
      float qd = EXP2F(acc1[mt][3] - base) + EPSF;
      qtp[mt].x = pk2bf(qa, qb);
      qtp[mt].y = pk2bf(qc, qd);
    }

    // ---- GEMM2: out[16n x 64e] over pos-space; 5th tile = kc hi/lo ----
    f32x4 acc2[5];
#pragma unroll
    for (int et = 0; et < 5; ++et) acc2[et] = (f32x4){0.f, 0.f, 0.f, 0.f};
#pragma unroll
    for (int w = 0; w < 8; ++w) {
      const int colb = ((w ^ b6) << 6) + gsw;
      short8 b0 = *(const short8*)(scc + colb);
      short8 b1 = *(const short8*)(scc + colb + 8192);
      short8 b2 = *(const short8*)(scc + colb + 16384);
      short8 b3 = *(const short8*)(scc + colb + 24576);
      short8 bd = *(const short8*)(sc2c + colb);
      u32x4 av = {qtp[2 * w].x, qtp[2 * w].y, qtp[2 * w + 1].x, qtp[2 * w + 1].y};
      short8 a = __builtin_bit_cast(short8, av);
      acc2[0] = __builtin_amdgcn_mfma_f32_16x16x32_bf16(a, b0, acc2[0], 0, 0, 0);
      acc2[1] = __builtin_amdgcn_mfma_f32_16x16x32_bf16(a, b1, acc2[1], 0, 0, 0);
      acc2[2] = __builtin_amdgcn_mfma_f32_16x16x32_bf16(a, b2, acc2[2], 0, 0, 0);
      acc2[3] = __builtin_amdgcn_mfma_f32_16x16x32_bf16(a, b3, acc2[3], 0, 0, 0);
      acc2[4] = __builtin_amdgcn_mfma_f32_16x16x32_bf16(a, bd, acc2[4], 0, 0, 0);
    }

    // ---- den broadcast + divide + store (lane: n = g*4+r, e = et*16+c) ----
    float* ot = obase + (size_t)tt * 16 * 64;
#pragma unroll
    for (int r = 0; r < 4; ++r) {
      float den = __shfl(acc2[4][r], g * 16) + __shfl(acc2[4][r], g * 16 + 1);
      float rinv = 1.0f / den;
      int n = g * 4 + r;
#pragma unroll
      for (int et = 0; et < 4; ++et)
        ot[(size_t)n * 64 + et * 16 + c] = acc2[et][r] * rinv;
    }
  }
}

extern "C" void kernel_launch(void* const* d_in, const int* in_sizes, int n_in,
                              void* d_out, int out_size, void* d_ws, size_t ws_size,
                              hipStream_t stream) {
  (void)in_sizes; (void)n_in; (void)out_size;
  const float* qp = (const float*)d_in[0];
  const float* kp = (const float*)d_in[1];
  const float* vp = (const float*)d_in[2];
  const float* proj = (const float*)d_in[3];
  float* outp = (float*)d_out;

  int nchunk = 8;
  while (nchunk > 1) {
    size_t fl = 64 + (size_t)nchunk * (2097152 + 32768 + 8192);
    size_t needed = fl * 4 + (size_t)(2097152 + 32768 + 32768 + 16384) * 2;
    if (needed <= ws_size) break;
    nchunk >>= 1;
  }

  float* wsf = (float*)d_ws;
  unsigned int* gmaxb = (unsigned int*)d_ws;
  float* ctxp = wsf + 64;
  float* kexpp = ctxp + (size_t)nchunk * 128 * 64 * 256;
  float* vsump = kexpp + (size_t)nchunk * 128 * 256;
  unsigned short* ctxt = (unsigned short*)(vsump + (size_t)nchunk * 128 * 64);
  unsigned short* kchi = ctxt + (size_t)128 * 64 * 256;
  unsigned short* kclo = kchi + 128 * 256;
  unsigned short* projb = kclo + 128 * 256;

  hipMemsetAsync(d_ws, 0, 16, stream);
  hipLaunchKernelGGL(perf_prep, dim3(64), dim3(256), 0, stream, proj, projb);
  hipLaunchKernelGGL(perf_kpass, dim3(128 * nchunk), dim3(256), 0, stream,
                     kp, vp, proj, ctxp, kexpp, vsump, gmaxb, nchunk);
  hipLaunchKernelGGL(perf_rescale, dim3(128 * 8), dim3(256), 0, stream,
                     ctxp, kexpp, vsump, ctxt, kchi, kclo, gmaxb, nchunk);
  hipLaunchKernelGGL(perf_qpass, dim3(128 * 8), dim3(256), 0, stream,
                     qp, projb, ctxt, kchi, kclo, outp);
}